// Round 1
// baseline (3420.618 us; speedup 1.0000x reference)
//
#include <hip/hip_runtime.h>
#include <math.h>

// SwarmSetEquivariantTorso — fp32 baseline.
// One wave (64 threads) per token; all per-token state in LDS (~15.4 KB).
// Linear layers: lane = output column, weights coalesced from global,
// activations broadcast from LDS as float4, 5 slot-rows accumulated in regs.

#define DOBS 198
#define NSLOT 5
#define NEG_INF_F (-3.402823466e38f)

struct P {
  const float *obs,*tok_w,*tok_b,*ln1_s,*ln1_b,
    *a1_qw,*a1_qb,*a1_kw,*a1_kb,*a1_vw,*a1_vb,*a1_ow,*a1_ob,
    *ln2_s,*ln2_b,*m1_w,*m1_b,*m2_w,*m2_b,*m3_w,*m3_b,
    *e1_w,*e1_b,*e2_w,*e2_b,*e3_w,*e3_b,
    *l1_w,*l1_b,*l2_w,*l2_b,*l3_w,*l3_b,
    *seed,*p_qw,*p_qb,*p_kw,*p_kb,*p_vw,*p_vb,*p_ow,*p_ob,
    *pr_w,*pr_b,*h1_w,*h1_b,*h2_w,*h2_b,*h3_w,*h3_b;
  float* out;
};
static_assert(sizeof(P) == 51*sizeof(void*), "P layout");

__device__ __forceinline__ float gelu_f(float x){
  // JAX approximate (tanh) gelu
  float t = 0.7978845608028654f * (x + 0.044715f*x*x*x);
  return 0.5f * x * (1.0f + tanhf(t));
}

__device__ __forceinline__ float wsum(float v){
  #pragma unroll
  for (int off=32; off>0; off>>=1) v += __shfl_xor(v, off, 64);
  return v;
}

// out[r][64*c+lane] = act( sum_k X[r*ldx+k] * W[k*N + 64*c + lane] + B[...] )
template<int NR, int NC>
__device__ __forceinline__ void linearK(
    const float* X, int ldx, int K,
    const float* __restrict__ W, const float* __restrict__ Bv,
    float* out, int ldo, int lane, bool dogelu)
{
  constexpr int N = NC*64;
  float acc[NR][NC];
  #pragma unroll
  for (int r=0;r<NR;r++)
    #pragma unroll
    for (int c=0;c<NC;c++) acc[r][c] = Bv[64*c + lane];
  for (int k=0;k<K;k+=4){
    float4 xv[NR];
    #pragma unroll
    for (int r=0;r<NR;r++) xv[r] = *(const float4*)(X + r*ldx + k);
    #pragma unroll
    for (int kk=0;kk<4;kk++){
      float w[NC];
      #pragma unroll
      for (int c=0;c<NC;c++) w[c] = W[(k+kk)*N + 64*c + lane];
      #pragma unroll
      for (int r=0;r<NR;r++){
        float xs = ((const float*)&xv[r])[kk];
        #pragma unroll
        for (int c=0;c<NC;c++) acc[r][c] = fmaf(xs, w[c], acc[r][c]);
      }
    }
  }
  #pragma unroll
  for (int r=0;r<NR;r++)
    #pragma unroll
    for (int c=0;c<NC;c++){
      float v = acc[r][c];
      if (dogelu) v = gelu_f(v);
      out[r*ldo + 64*c + lane] = v;
    }
}

__device__ __forceinline__ void ln5(const float* in, float* out,
                                    const float* __restrict__ sc,
                                    const float* __restrict__ bi, int lane){
  float scv = sc[lane], biv = bi[lane];
  #pragma unroll
  for (int i=0;i<5;i++){
    float x = in[i*64+lane];
    float m = wsum(x) * 0.015625f;
    float d = x - m;
    float v = wsum(d*d) * 0.015625f;
    out[i*64+lane] = d * (1.0f/sqrtf(v + 1e-6f)) * scv + biv;
  }
}

__global__ __launch_bounds__(64)
void swarm_fwd(P a)
{
  const int lane = threadIdx.x;
  const size_t t = blockIdx.x;
  __shared__ __align__(16) float s[3848];
  enum { OBS_=0, TIN_=200, TOK_=264, X_=584, Q_=904, K_=1224, V_=1544, Y_=1864,
         H1_=2184, H2_=2824, ATTN_=3464, MF_=3568, MSF_=3576, MANY_=3584,
         DIST_=3588, DMIN_=3616, DMEAN_=3624, LG_=3632, ALPHA_=3640, VRU_=3648,
         EGO_=3656, C_=3720, PE_=3784 };

  const float* obs = a.obs + t*DOBS;
  for (int i=lane;i<DOBS;i+=64) s[OBS_+i] = obs[i];
  __syncthreads();

  // ---- masks + pairwise distances ----
  if (lane < 5){
    int b = OBS_+32+15*lane;
    bool m = fabsf(s[b])>1e-6f || fabsf(s[b+1])>1e-6f || fabsf(s[b+2])>1e-6f;
    s[MF_+lane] = m ? 1.f : 0.f;
  }
  if (lane < 25){
    int i = lane/5, j = lane%5;
    float d2 = 0.f;
    #pragma unroll
    for (int d=0;d<3;d++){
      float ri = s[OBS_+32+15*i+d]; ri = isfinite(ri) ? ri : 0.f;
      float rj = s[OBS_+32+15*j+d]; rj = isfinite(rj) ? rj : 0.f;
      float df = ri - rj; d2 += df*df;
    }
    s[DIST_+lane] = sqrtf(d2);
  }
  __syncthreads();
  if (lane == 0){
    float any = (s[MF_]+s[MF_+1]+s[MF_+2]+s[MF_+3]+s[MF_+4]) > 0.f ? 1.f : 0.f;
    s[MANY_] = any;
    #pragma unroll
    for (int i=0;i<5;i++) s[MSF_+i] = (any>0.f) ? s[MF_+i] : (i==0?1.f:0.f);
  }
  if (lane < 5){
    int i = lane;
    float dmin = 1e9f, dsum = 0.f, cnt = 0.f;
    #pragma unroll
    for (int j=0;j<5;j++){
      if (j!=i && s[MF_+i]>0.5f && s[MF_+j]>0.5f){
        float dd = s[DIST_+i*5+j];
        dmin = fminf(dmin, dd); dsum += dd; cnt += 1.f;
      }
    }
    s[DMIN_+i]  = dmin;
    s[DMEAN_+i] = (cnt>0.f) ? dsum/(cnt+1e-9f) : 0.f;
  }
  __syncthreads();

  // ---- tok_in (5 x 12) ----
  if (lane < 60){
    int si = lane/12, c = lane%12, b = OBS_+32+15*si;
    float v;
    if (c < 4)       v = s[b+11+c];            // inv
    else if (c == 4) v = s[b+9];               // fre
    else if (c == 5) v = s[b+10];              // tem
    else if (c < 9)  v = s[b+6+(c-6)];         // att
    else if (c == 9){ float a0=s[b+6],a1=s[b+7],a2=s[b+8];
                      v = sqrtf(a0*a0+a1*a1+a2*a2); } // att_norm
    else if (c ==10) v = s[DMIN_+si];
    else             v = s[DMEAN_+si];
    s[TIN_+si*12+c] = v;
  }
  __syncthreads();

  // ---- tok = gelu(tok_in @ tok_w + b), masked ----
  linearK<5,1>(s+TIN_, 12, 12, a.tok_w, a.tok_b, s+TOK_, 64, lane, true);
  #pragma unroll
  for (int i=0;i<5;i++) s[TOK_+i*64+lane] *= s[MF_+i];
  __syncthreads();

  // ---- slot self-attention ----
  ln5(s+TOK_, s+X_, a.ln1_s, a.ln1_b, lane);
  __syncthreads();
  linearK<5,1>(s+X_, 64, 64, a.a1_qw, a.a1_qb, s+Q_, 64, lane, false);
  linearK<5,1>(s+X_, 64, 64, a.a1_kw, a.a1_kb, s+K_, 64, lane, false);
  linearK<5,1>(s+X_, 64, 64, a.a1_vw, a.a1_vb, s+V_, 64, lane, false);
  __syncthreads();
  if (lane < 20){
    int h = lane/5, i = lane%5;
    bool mi = s[MSF_+i] > 0.5f;
    float lg[5], mx = NEG_INF_F;
    #pragma unroll
    for (int j=0;j<5;j++){
      float d = 0.f;
      #pragma unroll
      for (int dd=0;dd<16;dd++) d += s[Q_+i*64+h*16+dd]*s[K_+j*64+h*16+dd];
      bool mj = s[MSF_+j] > 0.5f;
      lg[j] = (mi && mj) ? d*0.25f : NEG_INF_F;
      mx = fmaxf(mx, lg[j]);
    }
    float sum = 0.f, ex[5];
    #pragma unroll
    for (int j=0;j<5;j++){ ex[j] = expf(lg[j]-mx); sum += ex[j]; }
    float inv = 1.0f/sum;
    #pragma unroll
    for (int j=0;j<5;j++) s[ATTN_+(h*5+i)*5+j] = ex[j]*inv;
  }
  __syncthreads();
  {
    int h = lane>>4;
    #pragma unroll
    for (int i=0;i<5;i++){
      float o = 0.f;
      #pragma unroll
      for (int j=0;j<5;j++) o += s[ATTN_+(h*5+i)*5+j]*s[V_+j*64+lane];
      s[X_+i*64+lane] = o;
    }
  }
  __syncthreads();
  linearK<5,1>(s+X_, 64, 64, a.a1_ow, a.a1_ob, s+Y_, 64, lane, false);
  #pragma unroll
  for (int i=0;i<5;i++) s[TOK_+i*64+lane] += s[Y_+i*64+lane]*s[MF_+i];
  __syncthreads();

  // ---- slot MLP ----
  ln5(s+TOK_, s+X_, a.ln2_s, a.ln2_b, lane);
  __syncthreads();
  linearK<5,2>(s+X_, 64, 64,   a.m1_w, a.m1_b, s+H1_, 128, lane, true);
  __syncthreads();
  linearK<5,2>(s+H1_,128,128,  a.m2_w, a.m2_b, s+H2_, 128, lane, true);
  __syncthreads();
  linearK<5,1>(s+H2_,128,128,  a.m3_w, a.m3_b, s+Y_,  64,  lane, false);
  #pragma unroll
  for (int i=0;i<5;i++)
    s[TOK_+i*64+lane] = (s[TOK_+i*64+lane] + s[Y_+i*64+lane]*s[MF_+i])*s[MF_+i];
  __syncthreads();

  // ---- ego MLP ----
  linearK<1,2>(s+OBS_, 32, 32,  a.e1_w, a.e1_b, s+H1_, 128, lane, true);
  __syncthreads();
  linearK<1,2>(s+H1_, 128,128,  a.e2_w, a.e2_b, s+H2_, 128, lane, true);
  __syncthreads();
  linearK<1,1>(s+H2_, 128,128,  a.e3_w, a.e3_b, s+EGO_, 64, lane, false);
  __syncthreads();

  // ---- slot logits MLP (input = concat(tok, ego_ctx)) ----
  #pragma unroll
  for (int i=0;i<5;i++){
    s[Q_+i*128+lane]    = s[TOK_+i*64+lane];
    s[Q_+i*128+64+lane] = s[EGO_+lane];
  }
  __syncthreads();
  linearK<5,2>(s+Q_, 128,128, a.l1_w, a.l1_b, s+H1_, 128, lane, true);
  __syncthreads();
  linearK<5,2>(s+H1_,128,128, a.l2_w, a.l2_b, s+H2_, 128, lane, true);
  __syncthreads();
  if (lane < 5){
    float d = a.l3_b[0];
    for (int k=0;k<128;k++) d += s[H2_+lane*128+k]*a.l3_w[k];
    s[LG_+lane] = d;
  }
  __syncthreads();
  if (lane == 0){
    float ml[5], mx = -1e9f;
    #pragma unroll
    for (int i=0;i<5;i++){ ml[i] = (s[MF_+i]>0.5f) ? s[LG_+i] : -1e9f; mx = fmaxf(mx, ml[i]); }
    float den = 0.f;
    #pragma unroll
    for (int i=0;i<5;i++){ float e = expf(ml[i]-mx)*s[MF_+i]; s[ALPHA_+i] = e; den += e; }
    float inv = 1.0f/(den + 1e-9f);
    #pragma unroll
    for (int i=0;i<5;i++) s[ALPHA_+i] *= inv;
  }
  __syncthreads();
  if (lane < 6){
    int w = lane/3, d = lane%3;
    float v = 0.f;
    #pragma unroll
    for (int i=0;i<5;i++) v += s[ALPHA_+i]*s[OBS_+32+15*i+w*3+d];
    s[VRU_+lane] = v;
  }

  // ---- pooling attention (seed query) ----
  s[X_+lane] = a.seed[lane];
  __syncthreads();
  linearK<1,1>(s+X_,  64, 64, a.p_qw, a.p_qb, s+Y_, 64, lane, false);   // qp
  linearK<5,1>(s+TOK_,64, 64, a.p_kw, a.p_kb, s+Q_, 64, lane, false);   // kp
  linearK<5,1>(s+TOK_,64, 64, a.p_vw, a.p_vb, s+K_, 64, lane, false);   // vp
  __syncthreads();
  if (lane < 4){
    int h = lane;
    float lg[5], mx = NEG_INF_F;
    #pragma unroll
    for (int j=0;j<5;j++){
      float d = 0.f;
      #pragma unroll
      for (int dd=0;dd<16;dd++) d += s[Y_+h*16+dd]*s[Q_+j*64+h*16+dd];
      lg[j] = (s[MSF_+j]>0.5f) ? d*0.25f : NEG_INF_F;
      mx = fmaxf(mx, lg[j]);
    }
    float sum = 0.f, ex[5];
    #pragma unroll
    for (int j=0;j<5;j++){ ex[j] = expf(lg[j]-mx); sum += ex[j]; }
    float inv = 1.0f/sum;
    #pragma unroll
    for (int j=0;j<5;j++) s[ATTN_+h*5+j] = ex[j]*inv;
  }
  __syncthreads();
  {
    int h = lane>>4;
    float o = 0.f;
    #pragma unroll
    for (int j=0;j<5;j++) o += s[ATTN_+h*5+j]*s[K_+j*64+lane];
    s[X_+lane] = o;
  }
  __syncthreads();
  linearK<1,1>(s+X_, 64, 64, a.p_ow, a.p_ob, s+C_, 64, lane, false);
  s[C_+lane] *= s[MANY_];

  // ---- pair embedding (K=10, scalar tail) ----
  {
    float acc = a.pr_b[lane];
    #pragma unroll
    for (int k=0;k<10;k++) acc += s[OBS_+107+k]*a.pr_w[k*64+lane];
    s[PE_+lane] = gelu_f(acc);
  }
  __syncthreads();

  // ---- head MLP: h_in = [ego(32), c(64), pe(64)] ----
  if (lane < 32) s[Q_+lane] = s[OBS_+lane];
  s[Q_+32+lane] = s[C_+lane];
  s[Q_+96+lane] = s[PE_+lane];
  __syncthreads();
  linearK<1,2>(s+Q_, 160,160, a.h1_w, a.h1_b, s+H1_, 128, lane, true);
  __syncthreads();
  linearK<1,2>(s+H1_,128,128, a.h2_w, a.h2_b, s+H2_, 128, lane, true);
  __syncthreads();
  linearK<1,2>(s+H2_,128,128, a.h3_w, a.h3_b, s+H1_, 128, lane, false);
  __syncthreads();

  float* o = a.out + t*134;
  o[lane]      = s[H1_+lane];
  o[64+lane]   = s[H1_+64+lane];
  if (lane < 6) o[128+lane] = s[VRU_+lane];
}

extern "C" void kernel_launch(void* const* d_in, const int* in_sizes, int n_in,
                              void* d_out, int out_size, void* d_ws, size_t ws_size,
                              hipStream_t stream)
{
  P a;
  const float** pp = reinterpret_cast<const float**>(&a);
  for (int i=0;i<50;i++) pp[i] = reinterpret_cast<const float*>(d_in[i]);
  a.out = reinterpret_cast<float*>(d_out);
  int ntok = in_sizes[0] / DOBS;   // 65536
  hipLaunchKernelGGL(swarm_fwd, dim3(ntok), dim3(64), 0, stream, a);
}

// Round 2
// 1620.197 us; speedup vs baseline: 2.1112x; 2.1112x over previous
//
#include <hip/hip_runtime.h>
#include <math.h>

// SwarmSetEquivariantTorso — fp32, register-blocked, wave-private LDS.
// Block = 256 threads = 4 waves; each wave owns 2 tokens (8 tokens/block).
// All LDS is wave-private -> no __syncthreads anywhere.
// Linear layers: lane = output column, weights coalesced from global (L2-hot),
// NR = 10 rows (2 tokens x 5 slots) share every weight load (10-20 FMA/load).

#define DOBS 198
#define TOKSZ 1616
#define OBS_ 0      // 128 (117 used; ter is UNUSED by the reference)
#define TOK_ 128    // 320
#define X_   448    // 320
#define H_   768    // 640
#define AUX_ 1408   // 208
// AUX sublayout
#define MF_    0
#define MSF_   5
#define MANY_  10
#define DMIN_  11
#define DMEAN_ 16
#define LG_    21
#define ALPHA_ 26
#define VRU_   31
#define DIST_  40   // 25 (dead after setup)
#define ATTN_  40   // 100 (reuses DIST space)
#define EGO_   144  // 64
#define QPBASE (8*TOKSZ)   // 4 waves x 64 shared q_pool
#define NEG_INF_F (-3.402823466e38f)

struct P {
  const float *obs,*tok_w,*tok_b,*ln1_s,*ln1_b,
    *a1_qw,*a1_qb,*a1_kw,*a1_kb,*a1_vw,*a1_vb,*a1_ow,*a1_ob,
    *ln2_s,*ln2_b,*m1_w,*m1_b,*m2_w,*m2_b,*m3_w,*m3_b,
    *e1_w,*e1_b,*e2_w,*e2_b,*e3_w,*e3_b,
    *l1_w,*l1_b,*l2_w,*l2_b,*l3_w,*l3_b,
    *seed,*p_qw,*p_qb,*p_kw,*p_kb,*p_vw,*p_vb,*p_ow,*p_ob,
    *pr_w,*pr_b,*h1_w,*h1_b,*h2_w,*h2_b,*h3_w,*h3_b;
  float* out;
};
static_assert(sizeof(P) == 51*sizeof(void*), "P layout");

__device__ __forceinline__ float gelu_f(float x){
  // exact tanh-gelu form; tanh via fast hw exp (precision headroom is ~1e7x)
  float t = 0.7978845608028654f * (x + 0.044715f*x*x*x);
  float e = __expf(2.0f*t);                 // inf for large t -> th=1; 0 -> th=-1
  float th = 1.0f - 2.0f/(e+1.0f);
  return 0.5f * x * (1.0f + th);
}

__device__ __forceinline__ float wsum(float v){
  #pragma unroll
  for (int off=32; off>0; off>>=1) v += __shfl_xor(v, off, 64);
  return v;
}

// acc[r][c] = Bv[64c+lane] + sum_k X[r][k] * W[k*N + 64c + lane]
// Row addressing via lambda xaddr(r,k) -> const float* (16B-aligned, reads float4).
template<int NR,int NC,typename XA>
__device__ __forceinline__ void lin_acc(
    XA xaddr, int K,
    const float* __restrict__ W, const float* __restrict__ Bv,
    float (&acc)[NR][NC], int lane)
{
  constexpr int N = NC*64;
  #pragma unroll
  for (int r=0;r<NR;r++)
    #pragma unroll
    for (int c=0;c<NC;c++) acc[r][c] = Bv[64*c + lane];
  const float* Wp = W + lane;
  for (int k=0;k<K;k+=4){
    float w[4][NC];
    #pragma unroll
    for (int kk=0;kk<4;kk++)
      #pragma unroll
      for (int c=0;c<NC;c++) w[kk][c] = Wp[(size_t)(k+kk)*N + 64*c];
    #pragma unroll
    for (int r=0;r<NR;r++){
      float4 xv = *(const float4*)xaddr(r,k);
      #pragma unroll
      for (int kk=0;kk<4;kk++){
        float xs = (&xv.x)[kk];
        #pragma unroll
        for (int c=0;c<NC;c++) acc[r][c] = fmaf(xs, w[kk][c], acc[r][c]);
      }
    }
  }
}

__device__ __forceinline__ void ln5(const float* in, float* out,
                                    const float* __restrict__ sc,
                                    const float* __restrict__ bi, int lane){
  float scv = sc[lane], biv = bi[lane];
  #pragma unroll
  for (int i=0;i<5;i++){
    float x = in[i*64+lane];
    float m = wsum(x) * 0.015625f;
    float d = x - m;
    float v = wsum(d*d) * 0.015625f;
    out[i*64+lane] = d * (1.0f/sqrtf(v + 1e-6f)) * scv + biv;
  }
}

__global__ __launch_bounds__(256,3)
void swarm_fwd(P a, int ntok)
{
  const int lane = threadIdx.x & 63;
  const int wv   = threadIdx.x >> 6;
  const long t0  = (long)blockIdx.x*8 + wv*2;
  __shared__ __align__(16) float s[QPBASE + 256];
  if (t0 >= ntok) return;          // no barriers in kernel -> early return safe
  float* tdp[2] = { s + (wv*2+0)*TOKSZ, s + (wv*2+1)*TOKSZ };
  float* qp = s + QPBASE + wv*64;

  // ---- load obs (first 117 floats only; ter unused) ----
  #pragma unroll
  for (int tt=0;tt<2;tt++){
    const float* obs = a.obs + (t0+tt)*DOBS;
    float* td = tdp[tt];
    #pragma unroll
    for (int i=0;i<2;i++){ int idx=i*64+lane; if (idx<117) td[OBS_+idx]=obs[idx]; }
  }

  // ---- masks, pair distances, tok_in ----
  #pragma unroll
  for (int tt=0;tt<2;tt++){
    float* td=tdp[tt]; float* ax=td+AUX_;
    if (lane<5){
      const float* b = td+OBS_+32+15*lane;
      ax[MF_+lane] = (fabsf(b[0])>1e-6f||fabsf(b[1])>1e-6f||fabsf(b[2])>1e-6f)?1.f:0.f;
    }
    if (lane<25){
      int i=lane/5, j=lane%5; float d2=0.f;
      #pragma unroll
      for (int d=0;d<3;d++){
        float ri=td[OBS_+32+15*i+d]; ri = isfinite(ri)?ri:0.f;
        float rj=td[OBS_+32+15*j+d]; rj = isfinite(rj)?rj:0.f;
        float df=ri-rj; d2 += df*df;
      }
      ax[DIST_+lane]=sqrtf(d2);
    }
    if (lane==0){
      float any = ax[MF_]+ax[MF_+1]+ax[MF_+2]+ax[MF_+3]+ax[MF_+4];
      float anyf = (any>0.f)?1.f:0.f; ax[MANY_]=anyf;
      #pragma unroll
      for (int i=0;i<5;i++) ax[MSF_+i] = (anyf>0.f)? ax[MF_+i] : (i==0?1.f:0.f);
    }
    if (lane<5){
      int i=lane; float dmin=1e9f,dsum=0.f,cnt=0.f;
      #pragma unroll
      for (int j=0;j<5;j++){
        if (j!=i && ax[MF_+i]>0.5f && ax[MF_+j]>0.5f){
          float dd=ax[DIST_+i*5+j];
          dmin=fminf(dmin,dd); dsum+=dd; cnt+=1.f;
        }
      }
      ax[DMIN_+i]=dmin;
      ax[DMEAN_+i]=(cnt>0.f)? dsum/(cnt+1e-9f) : 0.f;
    }
    if (lane<60){
      int si=lane/12, c=lane%12; const float* b=td+OBS_+32+15*si;
      float v;
      if (c<4)        v=b[11+c];
      else if (c==4)  v=b[9];
      else if (c==5)  v=b[10];
      else if (c<9)   v=b[6+(c-6)];
      else if (c==9){ float a0=b[6],a1=b[7],a2=b[8]; v=sqrtf(a0*a0+a1*a1+a2*a2); }
      else if (c==10) v=ax[DMIN_+si];
      else            v=ax[DMEAN_+si];
      td[X_+si*12+c]=v;     // tok_in staged in X
    }
  }

  auto XR    = [&](int r,int k){ return (const float*)(tdp[r/5]+X_+(r%5)*64+k); };
  auto TOKR  = [&](int r,int k){ return (const float*)(tdp[r/5]+TOK_+(r%5)*64+k); };
  auto HR128 = [&](int r,int k){ return (const float*)(tdp[r/5]+H_+(r%5)*128+k); };
  auto TR    = [&](int r,int k){ return (const float*)(tdp[r]+H_+k); };   // token rows in H

  // ---- tok = gelu(tok_in @ tok_w + b) * mask ----
  {
    float acc[10][1];
    lin_acc<10,1>([&](int r,int k){ return (const float*)(tdp[r/5]+X_+(r%5)*12+k); },
                  12, a.tok_w, a.tok_b, acc, lane);
    #pragma unroll
    for (int r=0;r<10;r++){
      float* td=tdp[r/5]; int ss=r%5;
      td[TOK_+ss*64+lane] = gelu_f(acc[r][0]) * td[AUX_+MF_+ss];
    }
  }

  // ---- slot self-attention ----
  #pragma unroll
  for (int tt=0;tt<2;tt++) ln5(tdp[tt]+TOK_, tdp[tt]+X_, a.ln1_s, a.ln1_b, lane);
  { float acc[10][1]; lin_acc<10,1>(XR,64,a.a1_kw,a.a1_kb,acc,lane);
    #pragma unroll
    for (int r=0;r<10;r++) tdp[r/5][H_+(r%5)*64+lane]=acc[r][0]; }        // K
  { float acc[10][1]; lin_acc<10,1>(XR,64,a.a1_vw,a.a1_vb,acc,lane);
    #pragma unroll
    for (int r=0;r<10;r++) tdp[r/5][H_+320+(r%5)*64+lane]=acc[r][0]; }    // V
  { float acc[10][1]; lin_acc<10,1>(XR,64,a.a1_qw,a.a1_qb,acc,lane);
    #pragma unroll
    for (int r=0;r<10;r++) tdp[r/5][X_+(r%5)*64+lane]=acc[r][0]; }        // Q -> X (after full read)

  #pragma unroll
  for (int tt=0;tt<2;tt++){
    float* td=tdp[tt]; float* ax=td+AUX_;
    if (lane<20){
      int h=lane/5, i=lane%5;
      bool mi = ax[MSF_+i]>0.5f;
      float lg[5], mx=NEG_INF_F;
      #pragma unroll
      for (int j=0;j<5;j++){
        float d=0.f;
        #pragma unroll
        for (int dd=0;dd<16;dd++) d += td[X_+i*64+h*16+dd]*td[H_+j*64+h*16+dd];
        bool mj = ax[MSF_+j]>0.5f;
        lg[j] = (mi&&mj)? d*0.25f : NEG_INF_F;
        mx = fmaxf(mx, lg[j]);
      }
      float sum=0.f, ex[5];
      #pragma unroll
      for (int j=0;j<5;j++){ ex[j]=__expf(lg[j]-mx); sum+=ex[j]; }
      float inv=1.0f/sum;
      #pragma unroll
      for (int j=0;j<5;j++) ax[ATTN_+(h*5+i)*5+j]=ex[j]*inv;
    }
    { // attn @ V  -> X
      int h=lane>>4;
      #pragma unroll
      for (int i=0;i<5;i++){
        float o=0.f;
        #pragma unroll
        for (int j=0;j<5;j++) o += ax[ATTN_+(h*5+i)*5+j]*td[H_+320+j*64+lane];
        td[X_+i*64+lane]=o;
      }
    }
  }
  { float acc[10][1]; lin_acc<10,1>(XR,64,a.a1_ow,a.a1_ob,acc,lane);      // o-proj
    #pragma unroll
    for (int r=0;r<10;r++){
      float* td=tdp[r/5]; int ss=r%5;
      td[TOK_+ss*64+lane] += acc[r][0]*td[AUX_+MF_+ss];
    } }

  // ---- slot MLP ----
  #pragma unroll
  for (int tt=0;tt<2;tt++) ln5(tdp[tt]+TOK_, tdp[tt]+X_, a.ln2_s, a.ln2_b, lane);
  { float acc[10][2]; lin_acc<10,2>(XR,64,a.m1_w,a.m1_b,acc,lane);
    #pragma unroll
    for (int r=0;r<10;r++){ float* td=tdp[r/5]; int ss=r%5;
      td[H_+ss*128+lane]=gelu_f(acc[r][0]); td[H_+ss*128+64+lane]=gelu_f(acc[r][1]); } }
  { float acc[10][2]; lin_acc<10,2>(HR128,128,a.m2_w,a.m2_b,acc,lane);
    #pragma unroll
    for (int r=0;r<10;r++){ float* td=tdp[r/5]; int ss=r%5;
      td[H_+ss*128+lane]=gelu_f(acc[r][0]); td[H_+ss*128+64+lane]=gelu_f(acc[r][1]); } }
  { float acc[10][1]; lin_acc<10,1>(HR128,128,a.m3_w,a.m3_b,acc,lane);
    #pragma unroll
    for (int r=0;r<10;r++){ float* td=tdp[r/5]; int ss=r%5;
      float m=td[AUX_+MF_+ss];
      td[TOK_+ss*64+lane]=(td[TOK_+ss*64+lane]+acc[r][0]*m)*m; } }

  // ---- ego MLP (uses H token rows; H free now) ----
  { float acc[2][2];
    lin_acc<2,2>([&](int r,int k){ return (const float*)(tdp[r]+OBS_+k); },32,a.e1_w,a.e1_b,acc,lane);
    #pragma unroll
    for (int r=0;r<2;r++){ tdp[r][H_+lane]=gelu_f(acc[r][0]); tdp[r][H_+64+lane]=gelu_f(acc[r][1]); } }
  { float acc[2][2]; lin_acc<2,2>(TR,128,a.e2_w,a.e2_b,acc,lane);
    #pragma unroll
    for (int r=0;r<2;r++){ tdp[r][H_+lane]=gelu_f(acc[r][0]); tdp[r][H_+64+lane]=gelu_f(acc[r][1]); } }
  { float acc[2][1]; lin_acc<2,1>(TR,128,a.e3_w,a.e3_b,acc,lane);
    #pragma unroll
    for (int r=0;r<2;r++) tdp[r][AUX_+EGO_+lane]=acc[r][0]; }

  // ---- logits MLP: input cat(tok_slot, ego_ctx) ----
  { float acc[10][2];
    lin_acc<10,2>([&](int r,int k){ float* td=tdp[r/5];
        return (const float*)((k<64)? td+TOK_+(r%5)*64+k : td+AUX_+EGO_+(k-64)); },
      128, a.l1_w, a.l1_b, acc, lane);
    #pragma unroll
    for (int r=0;r<10;r++){ float* td=tdp[r/5]; int ss=r%5;
      td[H_+ss*128+lane]=gelu_f(acc[r][0]); td[H_+ss*128+64+lane]=gelu_f(acc[r][1]); } }
  { float acc[10][2]; lin_acc<10,2>(HR128,128,a.l2_w,a.l2_b,acc,lane);
    #pragma unroll
    for (int r=0;r<10;r++){ float* td=tdp[r/5]; int ss=r%5;
      td[H_+ss*128+lane]=gelu_f(acc[r][0]); td[H_+ss*128+64+lane]=gelu_f(acc[r][1]); } }
  #pragma unroll
  for (int tt=0;tt<2;tt++){
    float* td=tdp[tt]; float* ax=td+AUX_;
    #pragma unroll
    for (int ss=0;ss<5;ss++){
      float p = td[H_+ss*128+lane]*a.l3_w[lane] + td[H_+ss*128+64+lane]*a.l3_w[64+lane];
      p = wsum(p);
      if (lane==0) ax[LG_+ss]=p+a.l3_b[0];
    }
    if (lane==0){
      float ml[5], mx=-1e9f;
      #pragma unroll
      for (int i=0;i<5;i++){ ml[i]=(ax[MF_+i]>0.5f)? ax[LG_+i] : -1e9f; mx=fmaxf(mx,ml[i]); }
      float den=0.f;
      #pragma unroll
      for (int i=0;i<5;i++){ float e=__expf(ml[i]-mx)*ax[MF_+i]; ax[ALPHA_+i]=e; den+=e; }
      float inv=1.0f/(den+1e-9f);
      #pragma unroll
      for (int i=0;i<5;i++) ax[ALPHA_+i]*=inv;
    }
    if (lane<6){
      int w=lane/3, d=lane%3; float v=0.f;
      #pragma unroll
      for (int i=0;i<5;i++) v += ax[ALPHA_+i]*td[OBS_+32+15*i+w*3+d];
      ax[VRU_+lane]=v;
    }
  }

  // ---- pooling attention (seed query; q_pool computed once per wave) ----
  { float acc[1][1];
    lin_acc<1,1>([&](int,int k){ return a.seed+k; },64,a.p_qw,a.p_qb,acc,lane);
    qp[lane]=acc[0][0]; }
  { float acc[10][1]; lin_acc<10,1>(TOKR,64,a.p_kw,a.p_kb,acc,lane);
    #pragma unroll
    for (int r=0;r<10;r++) tdp[r/5][H_+(r%5)*64+lane]=acc[r][0]; }        // Kp
  { float acc[10][1]; lin_acc<10,1>(TOKR,64,a.p_vw,a.p_vb,acc,lane);
    #pragma unroll
    for (int r=0;r<10;r++) tdp[r/5][H_+320+(r%5)*64+lane]=acc[r][0]; }    // Vp
  #pragma unroll
  for (int tt=0;tt<2;tt++){
    float* td=tdp[tt]; float* ax=td+AUX_;
    if (lane<4){
      int h=lane;
      float lg[5], mx=NEG_INF_F;
      #pragma unroll
      for (int j=0;j<5;j++){
        float d=0.f;
        #pragma unroll
        for (int dd=0;dd<16;dd++) d += qp[h*16+dd]*td[H_+j*64+h*16+dd];
        lg[j] = (ax[MSF_+j]>0.5f)? d*0.25f : NEG_INF_F;
        mx = fmaxf(mx,lg[j]);
      }
      float sum=0.f, ex[5];
      #pragma unroll
      for (int j=0;j<5;j++){ ex[j]=__expf(lg[j]-mx); sum+=ex[j]; }
      float inv=1.0f/sum;
      #pragma unroll
      for (int j=0;j<5;j++) ax[ATTN_+h*5+j]=ex[j]*inv;
    }
    { int h=lane>>4; float o=0.f;
      #pragma unroll
      for (int j=0;j<5;j++) o += ax[ATTN_+h*5+j]*td[H_+320+j*64+lane];
      td[X_+lane]=o; }
  }
  { float acc[2][1];
    lin_acc<2,1>([&](int r,int k){ return (const float*)(tdp[r]+X_+k); },64,a.p_ow,a.p_ob,acc,lane);
    #pragma unroll
    for (int r=0;r<2;r++) tdp[r][X_+32+lane]=acc[r][0]*tdp[r][AUX_+MANY_]; }  // c -> X[32:96]

  // ---- h_in = [ego | c | pair_emb] in X[0:160] ----
  #pragma unroll
  for (int tt=0;tt<2;tt++){
    float* td=tdp[tt];
    if (lane<32) td[X_+lane]=td[OBS_+lane];
    float pa=a.pr_b[lane];
    #pragma unroll
    for (int k=0;k<10;k++) pa += td[OBS_+107+k]*a.pr_w[k*64+lane];
    td[X_+96+lane]=gelu_f(pa);
  }

  // ---- head MLP ----
  { float acc[2][2];
    lin_acc<2,2>([&](int r,int k){ return (const float*)(tdp[r]+X_+k); },160,a.h1_w,a.h1_b,acc,lane);
    #pragma unroll
    for (int r=0;r<2;r++){ tdp[r][H_+lane]=gelu_f(acc[r][0]); tdp[r][H_+64+lane]=gelu_f(acc[r][1]); } }
  { float acc[2][2]; lin_acc<2,2>(TR,128,a.h2_w,a.h2_b,acc,lane);
    #pragma unroll
    for (int r=0;r<2;r++){ tdp[r][H_+lane]=gelu_f(acc[r][0]); tdp[r][H_+64+lane]=gelu_f(acc[r][1]); } }
  { float acc[2][2]; lin_acc<2,2>(TR,128,a.h3_w,a.h3_b,acc,lane);
    #pragma unroll
    for (int r=0;r<2;r++){
      float* o=a.out+(t0+r)*134;
      o[lane]=acc[r][0]; o[64+lane]=acc[r][1];
    } }
  #pragma unroll
  for (int tt=0;tt<2;tt++)
    if (lane<6) a.out[(t0+tt)*134+128+lane]=tdp[tt][AUX_+VRU_+lane];
}

extern "C" void kernel_launch(void* const* d_in, const int* in_sizes, int n_in,
                              void* d_out, int out_size, void* d_ws, size_t ws_size,
                              hipStream_t stream)
{
  P a;
  const float** pp = reinterpret_cast<const float**>(&a);
  for (int i=0;i<50;i++) pp[i] = reinterpret_cast<const float*>(d_in[i]);
  a.out = reinterpret_cast<float*>(d_out);
  int ntok = in_sizes[0] / DOBS;   // 65536
  int blocks = (ntok + 7) / 8;
  hipLaunchKernelGGL(swarm_fwd, dim3(blocks), dim3(256), 0, stream, a, ntok);
}

// Round 3
// 946.360 us; speedup vs baseline: 3.6145x; 1.7120x over previous
//
#include <hip/hip_runtime.h>
#include <math.h>

// SwarmSetEquivariantTorso — bf16 MFMA version.
// Block = 256 threads (4 waves) handles 16 tokens. All dense layers are
// block-level GEMMs on mfma_f32_16x16x32_bf16: A (activations) in bf16 LDS,
// B (weights) read from a pre-transposed bf16 image in d_ws (W_t[n][k], so a
// B-fragment is one global dwordx4). Glue (masks, LN, 5x5 softmaxes) is fp32
// vector code. Residual/tok-embed kept high precision where the 1e6-scale
// single-slot path needs it.

#define DOBS 198
#define NEG_INF_F (-3.402823466e38f)

typedef __bf16 v8bf __attribute__((ext_vector_type(8)));
typedef float  v4f  __attribute__((ext_vector_type(4)));

struct P {
  const float *obs,*tok_w,*tok_b,*ln1_s,*ln1_b,
    *a1_qw,*a1_qb,*a1_kw,*a1_kb,*a1_vw,*a1_vb,*a1_ow,*a1_ob,
    *ln2_s,*ln2_b,*m1_w,*m1_b,*m2_w,*m2_b,*m3_w,*m3_b,
    *e1_w,*e1_b,*e2_w,*e2_b,*e3_w,*e3_b,
    *l1_w,*l1_b,*l2_w,*l2_b,*l3_w,*l3_b,
    *seed,*p_qw,*p_qb,*p_kw,*p_kb,*p_vw,*p_vb,*p_ow,*p_ob,
    *pr_w,*pr_b,*h1_w,*h1_b,*h2_w,*h2_b,*h3_w,*h3_b;
  float* out;
};
static_assert(sizeof(P) == 51*sizeof(void*), "P layout");

// ws bf16 weight-image offsets (elements), layout W_t[n][k] per matrix
#define W_A1Q 0
#define W_A1K 4096
#define W_A1V 8192
#define W_A1O 12288
#define W_M1  16384
#define W_M2  24576
#define W_M3  40960
#define W_E1  49152
#define W_E2  53248
#define W_E3  69632
#define W_L1  77824
#define W_L2  94208
#define W_PK  110592
#define W_PV  114688
#define W_PO  118784
#define W_H1  122880
#define W_H2  143360
#define W_H3  159744
#define W_END 176128

__global__ __launch_bounds__(256)
void prep_w(P a, __bf16* ws)
{
  const float* srcs[18] = {a.a1_qw,a.a1_kw,a.a1_vw,a.a1_ow,a.m1_w,a.m2_w,a.m3_w,
                           a.e1_w,a.e2_w,a.e3_w,a.l1_w,a.l2_w,a.p_kw,a.p_vw,a.p_ow,
                           a.h1_w,a.h2_w,a.h3_w};
  const int Ks[18]   = {64,64,64,64,64,128,128,32,128,128,128,128,64,64,64,160,128,128};
  const int Ns[18]   = {64,64,64,64,128,128,64,128,128,64,128,128,64,64,64,128,128,128};
  const int offs[19] = {W_A1Q,W_A1K,W_A1V,W_A1O,W_M1,W_M2,W_M3,W_E1,W_E2,W_E3,
                        W_L1,W_L2,W_PK,W_PV,W_PO,W_H1,W_H2,W_H3,W_END};
  int idx = blockIdx.x*256 + threadIdx.x;
  if (idx >= W_END) return;
  int m = 0;
  while (idx >= offs[m+1]) m++;
  int e = idx - offs[m];
  int K = Ks[m], N = Ns[m];
  int n = e / K, k = e % K;
  ws[idx] = (__bf16)srcs[m][(size_t)k*N + n];   // W_t[n][k] = W[k][n]
}

__device__ __forceinline__ float gelu_f(float x){
  float t = 0.7978845608028654f * (x + 0.044715f*x*x*x);
  float e = __expf(2.0f*t);
  float th = 1.0f - 2.0f/(e+1.0f);
  return 0.5f * x * (1.0f + th);
}

__device__ __forceinline__ float wsum(float v){
  #pragma unroll
  for (int off=32; off>0; off>>=1) v += __shfl_xor(v, off, 64);
  return v;
}

// Block GEMM: D[M x N] = A[M x K] @ W[K x N] + bias, A bf16 LDS (row stride lda),
// W from global W_t[n][k] bf16. Tiles 16x16, K-step 32. epi(row0, col, c) gets
// 4 rows row0..row0+3 at column col.
template<typename E>
__device__ __forceinline__ void gemmW(const __bf16* A, int lda, int mtiles,
    const __bf16* __restrict__ Wt, int K, int ntiles, int KT,
    const float* __restrict__ bias, int wv, int lane, E epi)
{
  const int col = lane & 15, quad = lane >> 4;
  const int tiles = mtiles*ntiles;
  for (int t = wv; t < tiles; t += 4){
    int mt = t / ntiles, nt = t % ntiles;
    v4f c; float b0 = bias[nt*16+col];
    c[0]=b0; c[1]=b0; c[2]=b0; c[3]=b0;
    const __bf16* ap = A + (size_t)(mt*16+col)*lda + quad*8;
    const __bf16* bp = Wt + (size_t)(nt*16+col)*K + quad*8;
    for (int kt = 0; kt < KT; kt++){
      v8bf av = *(const v8bf*)(ap + kt*32);
      v8bf bv = *(const v8bf*)(bp + kt*32);
      c = __builtin_amdgcn_mfma_f32_16x16x32_bf16(av, bv, c, 0, 0, 0);
    }
    epi(mt*16 + quad*4, nt*16 + col, c);
  }
}

// LDS map (bytes, total 78016):
//  Ab   bf16[80][136]  @0      21760   (A buffer / f32 dist scratch early)
//  Bb   bf16[80][136]  @21760  21760
//  Tk   bf16[80][72]   @43520  11520   (residual tok)
//  Ur              @55040  10240   (OBSf f32 16x120 -> V bf16[80][64])
//  Sc              @65280   4096   (tok_in f32 80x12 -> attn bf16 16x100 -> ecx bf16 16x64)
//  Pe   bf16[16][64]   @69376   2048
//  Eg   bf16[16][40]   @71424   1280   (ego, K=32 + pad)
//  Ru   f32 [16][32]   @72704   2048   (r,u raw: 30 used)
//  Ax   f32 [816]      @74752   3264   (mf80|msf80|many16|lg80|alpha80|qp64|pattn320)
__global__ __launch_bounds__(256,2)
void swarm_mfma(P a, const __bf16* __restrict__ ws, int ntok)
{
  __shared__ char smem[78016] __attribute__((aligned(16)));
  __bf16* Ab = (__bf16*)smem;
  __bf16* Bb = (__bf16*)(smem+21760);
  __bf16* Tk = (__bf16*)(smem+43520);
  float*  OBSf = (float*)(smem+55040);
  __bf16* Cb   = (__bf16*)(smem+55040);
  float*  TOKIN= (float*)(smem+65280);
  __bf16* ATTb = (__bf16*)(smem+65280);
  __bf16* ECX  = (__bf16*)(smem+65280);
  __bf16* Pe = (__bf16*)(smem+69376);
  __bf16* Eg = (__bf16*)(smem+71424);
  float*  Ru = (float*)(smem+72704);
  float*  Ax = (float*)(smem+74752);
  float* mf    = Ax;        // [80]
  float* msf   = Ax+80;     // [80]
  float* many  = Ax+160;    // [16]
  float* lg    = Ax+176;    // [80]
  float* alpha = Ax+256;    // [80]
  float* qp    = Ax+336;    // [64]
  float* pattn = Ax+400;    // [320]

  const int tid  = threadIdx.x;
  const int lane = tid & 63;
  const int wv   = tid >> 6;
  const long t0  = (long)blockIdx.x*16;

  // ---- P0: obs load + pooling query ----
  for (int it=tid; it<16*117; it+=256){
    int tg=it/117, c=it-tg*117;
    long gt = t0+tg; if (gt>ntok-1) gt=ntok-1;
    OBSf[tg*120+c] = a.obs[gt*DOBS + c];
  }
  if (tid<64){
    float acc = a.p_qb[tid];
    for (int k=0;k<64;k++) acc += a.seed[k]*a.p_qw[k*64+tid];
    qp[tid]=acc;
  }
  __syncthreads();

  // ---- P1: masks + pair distances (dist scratch in Ab as f32) ----
  float* Df = (float*)Ab;
  for (int it=tid; it<16*25; it+=256){
    int tg=it/25, p=it-tg*25, i=p/5, j=p-i*5;
    const float* ob = OBSf + tg*120 + 32;
    float d2=0.f;
    #pragma unroll
    for (int d=0;d<3;d++){
      float ri=ob[15*i+d]; ri = isfinite(ri)?ri:0.f;
      float rj=ob[15*j+d]; rj = isfinite(rj)?rj:0.f;
      float df=ri-rj; d2 += df*df;
    }
    Df[tg*32+p]=sqrtf(d2);
  }
  if (tid<80){
    int tg=tid/5, s=tid-tg*5;
    const float* b = OBSf + tg*120 + 32 + 15*s;
    mf[tid] = (fabsf(b[0])>1e-6f||fabsf(b[1])>1e-6f||fabsf(b[2])>1e-6f)?1.f:0.f;
  }
  __syncthreads();

  // ---- P2: msf/many, dmin/dmean->tok_in, tok_in, ego, ru, pair_emb ----
  if (tid<16){
    float any = mf[tid*5]+mf[tid*5+1]+mf[tid*5+2]+mf[tid*5+3]+mf[tid*5+4];
    float anyf = (any>0.f)?1.f:0.f; many[tid]=anyf;
    #pragma unroll
    for (int i=0;i<5;i++) msf[tid*5+i] = (anyf>0.f)? mf[tid*5+i] : (i==0?1.f:0.f);
  }
  if (tid<80){
    int tg=tid/5, i=tid-tg*5;
    float dmin=1e9f,dsum=0.f,cnt=0.f;
    #pragma unroll
    for (int j=0;j<5;j++){
      if (j!=i && mf[tg*5+i]>0.5f && mf[tg*5+j]>0.5f){
        float dd=Df[tg*32+i*5+j];
        dmin=fminf(dmin,dd); dsum+=dd; cnt+=1.f;
      }
    }
    TOKIN[tid*12+10]=dmin;
    TOKIN[tid*12+11]=(cnt>0.f)? dsum/(cnt+1e-9f) : 0.f;
  }
  for (int it=tid; it<16*50; it+=256){
    int tg=it/50, q=it-tg*50, s=q/10, c=q-s*10;
    const float* b = OBSf + tg*120 + 32 + 15*s;
    float v;
    if (c<4)        v=b[11+c];
    else if (c==4)  v=b[9];
    else if (c==5)  v=b[10];
    else if (c<9)   v=b[6+(c-6)];
    else { float a0=b[6],a1=b[7],a2=b[8]; v=sqrtf(a0*a0+a1*a1+a2*a2); }
    TOKIN[(tg*5+s)*12+c]=v;
  }
  for (int it=tid; it<16*32; it+=256){
    int tg=it>>5, c=it&31;
    Eg[tg*40+c] = (__bf16)OBSf[tg*120+c];
  }
  for (int it=tid; it<16*30; it+=256){
    int tg=it/30, c=it-tg*30;
    Ru[tg*32+c] = OBSf[tg*120+32+15*(c/6)+(c%6)];
  }
  for (int it=tid; it<16*64; it+=256){
    int tg=it>>6, c=it&63;
    float acc = a.pr_b[c];
    #pragma unroll
    for (int k=0;k<10;k++) acc += OBSf[tg*120+107+k]*a.pr_w[k*64+c];
    Pe[tg*64+c] = (__bf16)gelu_f(acc);
  }
  __syncthreads();

  // ---- P3: tok embed (fp32, K=12) + mask + ln1 -> Ab[:,0:64] ----
  for (int r=wv*20; r<wv*20+20; r++){
    float acc = a.tok_b[lane];
    #pragma unroll
    for (int k=0;k<12;k++) acc += TOKIN[r*12+k]*a.tok_w[k*64+lane];
    float t = gelu_f(acc)*mf[r];
    Tk[r*72+lane] = (__bf16)t;
    float m = wsum(t)*(1.f/64.f);
    float d = t-m;
    float v = wsum(d*d)*(1.f/64.f);
    Ab[r*136+lane] = (__bf16)(d*(1.0f/sqrtf(v+1e-6f))*a.ln1_s[lane]+a.ln1_b[lane]);
  }
  __syncthreads();

  // ---- G1/G2/G3: K,V,Q projections ----
  gemmW(Ab,136,5, ws+W_A1K,64,4,2, a.a1_kb, wv,lane,
    [&](int r0,int cn,v4f c){
      #pragma unroll
      for (int r=0;r<4;r++) Bb[(r0+r)*136+64+cn]=(__bf16)c[r]; });
  gemmW(Ab,136,5, ws+W_A1V,64,4,2, a.a1_vb, wv,lane,
    [&](int r0,int cn,v4f c){
      #pragma unroll
      for (int r=0;r<4;r++) Cb[(r0+r)*64+cn]=(__bf16)c[r]; });
  gemmW(Ab,136,5, ws+W_A1Q,64,4,2, a.a1_qb, wv,lane,
    [&](int r0,int cn,v4f c){
      #pragma unroll
      for (int r=0;r<4;r++) Bb[(r0+r)*136+cn]=(__bf16)c[r]; });
  __syncthreads();

  // ---- attn weights (token,h,i) ----
  for (int it=tid; it<320; it+=256){
    int tg=it/20, rem=it-tg*20, h=rem/5, i=rem-h*5;
    bool mi = msf[tg*5+i]>0.5f;
    float lgv[5], mx=NEG_INF_F;
    #pragma unroll
    for (int j=0;j<5;j++){
      float d=0.f;
      #pragma unroll
      for (int dd=0;dd<16;dd++)
        d += (float)Bb[(tg*5+i)*136+h*16+dd]*(float)Bb[(tg*5+j)*136+64+h*16+dd];
      bool mj = msf[tg*5+j]>0.5f;
      lgv[j] = (mi&&mj)? d*0.25f : NEG_INF_F;
      mx = fmaxf(mx,lgv[j]);
    }
    float sum=0.f, ex[5];
    #pragma unroll
    for (int j=0;j<5;j++){ ex[j]=__expf(lgv[j]-mx); sum+=ex[j]; }
    float inv=1.0f/sum;
    #pragma unroll
    for (int j=0;j<5;j++) ATTb[tg*100+(h*5+i)*5+j]=(__bf16)(ex[j]*inv);
  }
  __syncthreads();

  // ---- o = attn @ V -> Ab[:,0:64] ----
  for (int r=wv*20; r<wv*20+20; r++){
    int tg=r/5, i=r-tg*5, h=lane>>4;
    float o=0.f;
    #pragma unroll
    for (int j=0;j<5;j++)
      o += (float)ATTb[tg*100+(h*5+i)*5+j]*(float)Cb[(tg*5+j)*64+lane];
    Ab[r*136+lane]=(__bf16)o;
  }
  __syncthreads();

  // ---- G4: o-proj + residual -> Tk ----
  gemmW(Ab,136,5, ws+W_A1O,64,4,2, a.a1_ob, wv,lane,
    [&](int r0,int cn,v4f c){
      #pragma unroll
      for (int r=0;r<4;r++){
        int R=r0+r;
        Tk[R*72+cn] = (__bf16)((float)Tk[R*72+cn] + c[r]*mf[R]);
      } });
  __syncthreads();

  // ---- ln2 -> Ab[:,0:64] ----
  for (int r=wv*20; r<wv*20+20; r++){
    float x = (float)Tk[r*72+lane];
    float m = wsum(x)*(1.f/64.f);
    float d = x-m;
    float v = wsum(d*d)*(1.f/64.f);
    Ab[r*136+lane] = (__bf16)(d*(1.0f/sqrtf(v+1e-6f))*a.ln2_s[lane]+a.ln2_b[lane]);
  }
  __syncthreads();

  // ---- slot MLP: m1,m2,m3 ----
  gemmW(Ab,136,5, ws+W_M1,64,8,2, a.m1_b, wv,lane,
    [&](int r0,int cn,v4f c){
      #pragma unroll
      for (int r=0;r<4;r++) Bb[(r0+r)*136+cn]=(__bf16)gelu_f(c[r]); });
  __syncthreads();
  gemmW(Bb,136,5, ws+W_M2,128,8,4, a.m2_b, wv,lane,
    [&](int r0,int cn,v4f c){
      #pragma unroll
      for (int r=0;r<4;r++) Ab[(r0+r)*136+cn]=(__bf16)gelu_f(c[r]); });
  __syncthreads();
  gemmW(Ab,136,5, ws+W_M3,128,4,4, a.m3_b, wv,lane,
    [&](int r0,int cn,v4f c){
      #pragma unroll
      for (int r=0;r<4;r++){
        int R=r0+r; float mm=mf[R];
        Tk[R*72+cn] = (__bf16)(((float)Tk[R*72+cn] + c[r]*mm)*mm);
      } });
  __syncthreads();

  // ---- ego MLP (M=16 token rows) ----
  gemmW(Eg,40,1, ws+W_E1,32,8,1, a.e1_b, wv,lane,
    [&](int r0,int cn,v4f c){
      #pragma unroll
      for (int r=0;r<4;r++) Bb[(r0+r)*136+cn]=(__bf16)gelu_f(c[r]); });
  __syncthreads();
  gemmW(Bb,136,1, ws+W_E2,128,8,4, a.e2_b, wv,lane,
    [&](int r0,int cn,v4f c){
      #pragma unroll
      for (int r=0;r<4;r++) Ab[(r0+r)*136+cn]=(__bf16)gelu_f(c[r]); });
  __syncthreads();
  gemmW(Ab,136,1, ws+W_E3,128,4,4, a.e3_b, wv,lane,
    [&](int r0,int cn,v4f c){
      #pragma unroll
      for (int r=0;r<4;r++) ECX[(r0+r)*64+cn]=(__bf16)c[r]; });
  __syncthreads();

  // ---- build l1 input: Ab[:,0:64]=tok, [64:128]=ego_ctx ----
  for (int it=tid; it<80*64; it+=256){
    int r=it>>6, c=it&63;
    Ab[r*136+c]    = Tk[r*72+c];
    Ab[r*136+64+c] = ECX[(r/5)*64+c];
  }
  __syncthreads();

  // ---- l1, l2 ----
  gemmW(Ab,136,5, ws+W_L1,128,8,4, a.l1_b, wv,lane,
    [&](int r0,int cn,v4f c){
      #pragma unroll
      for (int r=0;r<4;r++) Bb[(r0+r)*136+cn]=(__bf16)gelu_f(c[r]); });
  __syncthreads();
  gemmW(Bb,136,5, ws+W_L2,128,8,4, a.l2_b, wv,lane,
    [&](int r0,int cn,v4f c){
      #pragma unroll
      for (int r=0;r<4;r++) Ab[(r0+r)*136+cn]=(__bf16)gelu_f(c[r]); });
  __syncthreads();

  // ---- l3 logits (dot-128 per slot-row) ----
  {
    float wA = a.l3_w[lane], wB = a.l3_w[64+lane];
    for (int r=wv*20; r<wv*20+20; r++){
      float v = (float)Ab[r*136+lane]*wA + (float)Ab[r*136+64+lane]*wB;
      v = wsum(v);
      if (lane==0) lg[r] = v + a.l3_b[0];
    }
  }
  __syncthreads();
  if (tid<16){
    float ml[5], mx=-1e9f;
    #pragma unroll
    for (int i=0;i<5;i++){ ml[i]=(mf[tid*5+i]>0.5f)? lg[tid*5+i] : -1e9f; mx=fmaxf(mx,ml[i]); }
    float den=0.f;
    #pragma unroll
    for (int i=0;i<5;i++){ float e=__expf(ml[i]-mx)*mf[tid*5+i]; alpha[tid*5+i]=e; den+=e; }
    float inv=1.0f/(den+1e-9f);
    #pragma unroll
    for (int i=0;i<5;i++) alpha[tid*5+i]*=inv;
  }
  __syncthreads();
  if (tid<96){
    int tg=tid/6, c=tid-tg*6;
    float v=0.f;
    #pragma unroll
    for (int i=0;i<5;i++) v += alpha[tg*5+i]*Ru[tg*32+i*6+c];
    if (t0+tg<ntok) a.out[(t0+tg)*134+128+c]=v;
  }

  // ---- pooling: kp, vp ----
  gemmW(Tk,72,5, ws+W_PK,64,4,2, a.p_kb, wv,lane,
    [&](int r0,int cn,v4f c){
      #pragma unroll
      for (int r=0;r<4;r++) Bb[(r0+r)*136+cn]=(__bf16)c[r]; });
  gemmW(Tk,72,5, ws+W_PV,64,4,2, a.p_vb, wv,lane,
    [&](int r0,int cn,v4f c){
      #pragma unroll
      for (int r=0;r<4;r++) Bb[(r0+r)*136+64+cn]=(__bf16)c[r]; });
  __syncthreads();

  // ---- pooling attn weights ----
  if (tid<64){
    int tg=tid>>2, h=tid&3;
    float lgv[5], mx=NEG_INF_F;
    #pragma unroll
    for (int j=0;j<5;j++){
      float d=0.f;
      #pragma unroll
      for (int dd=0;dd<16;dd++)
        d += qp[h*16+dd]*(float)Bb[(tg*5+j)*136+h*16+dd];
      lgv[j] = (msf[tg*5+j]>0.5f)? d*0.25f : NEG_INF_F;
      mx = fmaxf(mx,lgv[j]);
    }
    float sum=0.f, ex[5];
    #pragma unroll
    for (int j=0;j<5;j++){ ex[j]=__expf(lgv[j]-mx); sum+=ex[j]; }
    float inv=1.0f/sum;
    #pragma unroll
    for (int j=0;j<5;j++) pattn[tg*20+h*5+j]=ex[j]*inv;
  }
  __syncthreads();

  // ---- pooled c (pre o-proj) -> Ab rows 0..15 [0:64] ----
  for (int it=tid; it<16*64; it+=256){
    int tg=it>>6, c=it&63, h=c>>4;
    float o=0.f;
    #pragma unroll
    for (int j=0;j<5;j++)
      o += pattn[tg*20+h*5+j]*(float)Bb[(tg*5+j)*136+64+c];
    Ab[tg*136+c]=(__bf16)o;
  }
  __syncthreads();

  // ---- G15: p_ow, sync-before-epi (epi overwrites its own A region) ----
  {
    const int col=lane&15, quad=lane>>4;
    int nt=wv;
    v4f c; float b0=a.p_ob[nt*16+col];
    c[0]=b0; c[1]=b0; c[2]=b0; c[3]=b0;
    const __bf16* ap = Ab + (size_t)col*136 + quad*8;
    const __bf16* bp = ws + W_PO + (size_t)(nt*16+col)*64 + quad*8;
    #pragma unroll
    for (int kt=0;kt<2;kt++){
      v8bf av=*(const v8bf*)(ap+kt*32);
      v8bf bv=*(const v8bf*)(bp+kt*32);
      c=__builtin_amdgcn_mfma_f32_16x16x32_bf16(av,bv,c,0,0,0);
    }
    __syncthreads();
    #pragma unroll
    for (int r=0;r<4;r++){
      int R=quad*4+r;
      Ab[R*136 + nt*16+col] = (__bf16)(c[r]*many[R]);
    }
  }
  // pe -> Ab rows 0..15 [64:128]
  for (int it=tid; it<16*64; it+=256){
    int tg=it>>6, c=it&63;
    Ab[tg*136+64+c] = Pe[tg*64+c];
  }
  __syncthreads();

  // ---- h1: two-stage (ego K=32 @ h1_w[0:32] + [c|pe] K=128 @ h1_w[32:160]) ----
  {
    const int col=lane&15, quad=lane>>4;
    for (int t=wv; t<8; t+=4){
      int nt=t;
      v4f c; float b0=a.h1_b[nt*16+col];
      c[0]=b0; c[1]=b0; c[2]=b0; c[3]=b0;
      {
        v8bf av=*(const v8bf*)(Eg + (size_t)col*40 + quad*8);
        v8bf bv=*(const v8bf*)(ws + W_H1 + (size_t)(nt*16+col)*160 + quad*8);
        c=__builtin_amdgcn_mfma_f32_16x16x32_bf16(av,bv,c,0,0,0);
      }
      #pragma unroll
      for (int kt=0;kt<4;kt++){
        v8bf av=*(const v8bf*)(Ab + (size_t)col*136 + kt*32 + quad*8);
        v8bf bv=*(const v8bf*)(ws + W_H1 + (size_t)(nt*16+col)*160 + 32 + kt*32 + quad*8);
        c=__builtin_amdgcn_mfma_f32_16x16x32_bf16(av,bv,c,0,0,0);
      }
      #pragma unroll
      for (int r=0;r<4;r++) Bb[(quad*4+r)*136 + nt*16+col]=(__bf16)gelu_f(c[r]);
    }
  }
  __syncthreads();

  // ---- h2 ----
  gemmW(Bb,136,1, ws+W_H2,128,8,4, a.h2_b, wv,lane,
    [&](int r0,int cn,v4f c){
      #pragma unroll
      for (int r=0;r<4;r++) Ab[(r0+r)*136+cn]=(__bf16)gelu_f(c[r]); });
  __syncthreads();

  // ---- h3 -> global out ----
  gemmW(Ab,136,1, ws+W_H3,128,8,4, a.h3_b, wv,lane,
    [&](int r0,int cn,v4f c){
      #pragma unroll
      for (int r=0;r<4;r++){
        long tk = t0 + r0 + r;
        if (tk<ntok) a.out[tk*134+cn]=c[r];
      } });
}

extern "C" void kernel_launch(void* const* d_in, const int* in_sizes, int n_in,
                              void* d_out, int out_size, void* d_ws, size_t ws_size,
                              hipStream_t stream)
{
  P a;
  const float** pp = reinterpret_cast<const float**>(&a);
  for (int i=0;i<50;i++) pp[i] = reinterpret_cast<const float*>(d_in[i]);
  a.out = reinterpret_cast<float*>(d_out);
  int ntok = in_sizes[0] / DOBS;   // 65536

  __bf16* ws = reinterpret_cast<__bf16*>(d_ws);
  hipLaunchKernelGGL(prep_w, dim3((W_END+255)/256), dim3(256), 0, stream, a, ws);
  hipLaunchKernelGGL(swarm_mfma, dim3((ntok+15)/16), dim3(256), 0, stream, a, ws, ntok);
}

// Round 4
// 874.797 us; speedup vs baseline: 3.9102x; 1.0818x over previous
//
#include <hip/hip_runtime.h>
#include <math.h>

// SwarmSetEquivariantTorso — bf16 MFMA, 12 tokens/block, 3 blocks/CU.
// Block = 256 threads (4 waves) handles 12 tokens (60 slot rows, padded 64).
// LDS 53.2KB -> 3 blocks/CU (12 waves). V lives in Ab[:,64:128] (no 3rd buf),
// Tk overlays the dead OBS region. Whole smem zero-inited once (pad rows safe).
// Attention glue vectorized with b128 bf16 loads. prep_w = tiled transpose.

#define DOBS 198
#define NEG_INF_F (-3.402823466e38f)

typedef __bf16 v8bf __attribute__((ext_vector_type(8)));
typedef float  v4f  __attribute__((ext_vector_type(4)));

struct P {
  const float *obs,*tok_w,*tok_b,*ln1_s,*ln1_b,
    *a1_qw,*a1_qb,*a1_kw,*a1_kb,*a1_vw,*a1_vb,*a1_ow,*a1_ob,
    *ln2_s,*ln2_b,*m1_w,*m1_b,*m2_w,*m2_b,*m3_w,*m3_b,
    *e1_w,*e1_b,*e2_w,*e2_b,*e3_w,*e3_b,
    *l1_w,*l1_b,*l2_w,*l2_b,*l3_w,*l3_b,
    *seed,*p_qw,*p_qb,*p_kw,*p_kb,*p_vw,*p_vb,*p_ow,*p_ob,
    *pr_w,*pr_b,*h1_w,*h1_b,*h2_w,*h2_b,*h3_w,*h3_b;
  float* out;
};
static_assert(sizeof(P) == 51*sizeof(void*), "P layout");

// ws bf16 weight image, W_t[n][k] per matrix (element offsets)
#define W_A1Q 0
#define W_A1K 4096
#define W_A1V 8192
#define W_A1O 12288
#define W_M1  16384
#define W_M2  24576
#define W_M3  40960
#define W_E1  49152
#define W_E2  53248
#define W_E3  69632
#define W_L1  77824
#define W_L2  94208
#define W_PK  110592
#define W_PV  114688
#define W_PO  118784
#define W_H1  122880
#define W_H2  143360
#define W_H3  159744
#define W_END 176128

// coalesced 32x32 tiled transpose fp32 -> bf16 W_t image
__global__ __launch_bounds__(256)
void prep_w(P a, __bf16* ws)
{
  const float* srcs[18] = {a.a1_qw,a.a1_kw,a.a1_vw,a.a1_ow,a.m1_w,a.m2_w,a.m3_w,
                           a.e1_w,a.e2_w,a.e3_w,a.l1_w,a.l2_w,a.p_kw,a.p_vw,a.p_ow,
                           a.h1_w,a.h2_w,a.h3_w};
  const int Ks[18]   = {64,64,64,64,64,128,128,32,128,128,128,128,64,64,64,160,128,128};
  const int Ns[18]   = {64,64,64,64,128,128,64,128,128,64,128,128,64,64,64,128,128,128};
  const int offs[18] = {W_A1Q,W_A1K,W_A1V,W_A1O,W_M1,W_M2,W_M3,W_E1,W_E2,W_E3,
                        W_L1,W_L2,W_PK,W_PV,W_PO,W_H1,W_H2,W_H3};
  __shared__ float tile[32][33];
  int b = blockIdx.x, m = 0, acc = 0;
  for (; m < 18; m++){
    int t = (Ks[m]/32)*(Ns[m]/32);
    if (b < acc + t) break;
    acc += t;
  }
  int lt = b - acc, K = Ks[m], N = Ns[m];
  int ntile = N/32, kt = lt/ntile, nt = lt%ntile;
  int tx = threadIdx.x & 31, ty = threadIdx.x >> 5;   // 8 rows/pass
  const float* S = srcs[m];
  #pragma unroll
  for (int rr=0; rr<32; rr+=8)
    tile[ty+rr][tx] = S[(size_t)(kt*32+ty+rr)*N + nt*32+tx];
  __syncthreads();
  __bf16* D = ws + offs[m];
  #pragma unroll
  for (int rr=0; rr<32; rr+=8)
    D[(size_t)(nt*32+ty+rr)*K + kt*32+tx] = (__bf16)tile[tx][ty+rr];
}

__device__ __forceinline__ float gelu_f(float x){
  float t = 0.7978845608028654f * (x + 0.044715f*x*x*x);
  float e = __expf(2.0f*t);
  float th = 1.0f - 2.0f/(e+1.0f);
  return 0.5f * x * (1.0f + th);
}

__device__ __forceinline__ float wsum(float v){
  #pragma unroll
  for (int off=32; off>0; off>>=1) v += __shfl_xor(v, off, 64);
  return v;
}

__device__ __forceinline__ void load16f(const __bf16* p, float* f){
  v8bf a = *(const v8bf*)p, b = *(const v8bf*)(p+8);
  #pragma unroll
  for (int i=0;i<8;i++){ f[i]=(float)a[i]; f[8+i]=(float)b[i]; }
}

// Block GEMM: D[Mx N] = A @ W + bias; A bf16 LDS (stride lda), W global W_t[n][k].
template<typename E>
__device__ __forceinline__ void gemmW(const __bf16* A, int lda, int mtiles,
    const __bf16* __restrict__ Wt, int K, int ntiles, int KT,
    const float* __restrict__ bias, int wv, int lane, E epi)
{
  const int col = lane & 15, quad = lane >> 4;
  const int tiles = mtiles*ntiles;
  for (int t = wv; t < tiles; t += 4){
    int mt = t / ntiles, nt = t % ntiles;
    v4f c; float b0 = bias[nt*16+col];
    c[0]=b0; c[1]=b0; c[2]=b0; c[3]=b0;
    const __bf16* ap = A + (size_t)(mt*16+col)*lda + quad*8;
    const __bf16* bp = Wt + (size_t)(nt*16+col)*K + quad*8;
    for (int kt = 0; kt < KT; kt++){
      v8bf av = *(const v8bf*)(ap + kt*32);
      v8bf bv = *(const v8bf*)(bp + kt*32);
      c = __builtin_amdgcn_mfma_f32_16x16x32_bf16(av, bv, c, 0, 0, 0);
    }
    epi(mt*16 + quad*4, nt*16 + col, c);
  }
}

// LDS map (bytes), total 53168:
//  Ab  bf16[64][136] @0      17408  (A/B ping; V in cols 64..127; f32 dist early)
//  Bb  bf16[64][136] @17408  17408
//  TkO               @34816   9216  (OBSf f32 12x120 -> Tk bf16[64][72])
//  Sc                @44032   2880  (TOKIN f32 60x12 -> ATTb bf16 12x100 -> ECX 16x64)
//  Pe  bf16[12][64]  @46912   1536
//  Eg  bf16[12][40]  @48448    960
//  Ru  f32 [12][32]  @49408   1536
//  Ax  f32 [556]     @50944   2224  (mf60|msf60|many12|lg60|alpha60|qp64|pattn240)
__global__ __launch_bounds__(256,3)
void swarm_mfma(P a, const __bf16* __restrict__ ws, int ntok)
{
  __shared__ char smem[53168] __attribute__((aligned(16)));
  __bf16* Ab = (__bf16*)smem;
  __bf16* Bb = (__bf16*)(smem+17408);
  float*  OBSf = (float*)(smem+34816);
  __bf16* Tk   = (__bf16*)(smem+34816);
  float*  TOKIN= (float*)(smem+44032);
  __bf16* ATTb = (__bf16*)(smem+44032);
  __bf16* ECX  = (__bf16*)(smem+44032);
  __bf16* Pe = (__bf16*)(smem+46912);
  __bf16* Eg = (__bf16*)(smem+48448);
  float*  Ru = (float*)(smem+49408);
  float*  Ax = (float*)(smem+50944);
  float* mf    = Ax;        // [60]
  float* msf   = Ax+60;     // [60]
  float* many  = Ax+120;    // [12]
  float* lg    = Ax+132;    // [60]
  float* alpha = Ax+192;    // [60]
  float* qp    = Ax+252;    // [64]
  float* pattn = Ax+316;    // [240]

  const int tid  = threadIdx.x;
  const int lane = tid & 63;
  const int wv   = tid >> 6;
  const long t0  = (long)blockIdx.x*12;

  // ---- zero-init all smem (pad rows must be finite/zero) ----
  {
    float4* z = (float4*)smem;
    for (int i=tid; i<53168/16; i+=256) z[i] = float4{0.f,0.f,0.f,0.f};
  }
  __syncthreads();

  // ---- P0: obs load + pooling query ----
  for (int it=tid; it<12*117; it+=256){
    int tg=it/117, c=it-tg*117;
    long gt = t0+tg; if (gt>ntok-1) gt=ntok-1;
    OBSf[tg*120+c] = a.obs[gt*DOBS + c];
  }
  if (tid<64){
    float acc = a.p_qb[tid];
    for (int k=0;k<64;k++) acc += a.seed[k]*a.p_qw[k*64+tid];
    qp[tid]=acc;
  }
  __syncthreads();

  // ---- P1: masks + pair distances (dist scratch in Ab as f32) ----
  float* Df = (float*)Ab;
  for (int it=tid; it<12*25; it+=256){
    int tg=it/25, p=it-tg*25, i=p/5, j=p-i*5;
    const float* ob = OBSf + tg*120 + 32;
    float d2=0.f;
    #pragma unroll
    for (int d=0;d<3;d++){
      float ri=ob[15*i+d]; ri = isfinite(ri)?ri:0.f;
      float rj=ob[15*j+d]; rj = isfinite(rj)?rj:0.f;
      float df=ri-rj; d2 += df*df;
    }
    Df[tg*32+p]=sqrtf(d2);
  }
  if (tid<60){
    int tg=tid/5, s=tid-tg*5;
    const float* b = OBSf + tg*120 + 32 + 15*s;
    mf[tid] = (fabsf(b[0])>1e-6f||fabsf(b[1])>1e-6f||fabsf(b[2])>1e-6f)?1.f:0.f;
  }
  __syncthreads();

  // ---- P2: msf/many, dmin/dmean, tok_in, ego, ru, pair_emb ----
  if (tid<12){
    float any = mf[tid*5]+mf[tid*5+1]+mf[tid*5+2]+mf[tid*5+3]+mf[tid*5+4];
    float anyf = (any>0.f)?1.f:0.f; many[tid]=anyf;
    #pragma unroll
    for (int i=0;i<5;i++) msf[tid*5+i] = (anyf>0.f)? mf[tid*5+i] : (i==0?1.f:0.f);
  }
  if (tid<60){
    int tg=tid/5, i=tid-tg*5;
    float dmin=1e9f,dsum=0.f,cnt=0.f;
    #pragma unroll
    for (int j=0;j<5;j++){
      if (j!=i && mf[tg*5+i]>0.5f && mf[tg*5+j]>0.5f){
        float dd=Df[tg*32+i*5+j];
        dmin=fminf(dmin,dd); dsum+=dd; cnt+=1.f;
      }
    }
    TOKIN[tid*12+10]=dmin;
    TOKIN[tid*12+11]=(cnt>0.f)? dsum/(cnt+1e-9f) : 0.f;
  }
  for (int it=tid; it<12*50; it+=256){
    int tg=it/50, q=it-tg*50, s=q/10, c=q-s*10;
    const float* b = OBSf + tg*120 + 32 + 15*s;
    float v;
    if (c<4)        v=b[11+c];
    else if (c==4)  v=b[9];
    else if (c==5)  v=b[10];
    else if (c<9)   v=b[6+(c-6)];
    else { float a0=b[6],a1=b[7],a2=b[8]; v=sqrtf(a0*a0+a1*a1+a2*a2); }
    TOKIN[(tg*5+s)*12+c]=v;
  }
  for (int it=tid; it<12*32; it+=256){
    int tg=it>>5, c=it&31;
    Eg[tg*40+c] = (__bf16)OBSf[tg*120+c];
  }
  for (int it=tid; it<12*30; it+=256){
    int tg=it/30, c=it-tg*30;
    Ru[tg*32+c] = OBSf[tg*120+32+15*(c/6)+(c%6)];
  }
  for (int it=tid; it<12*64; it+=256){
    int tg=it>>6, c=it&63;
    float acc = a.pr_b[c];
    #pragma unroll
    for (int k=0;k<10;k++) acc += OBSf[tg*120+107+k]*a.pr_w[k*64+c];
    Pe[tg*64+c] = (__bf16)gelu_f(acc);
  }
  __syncthreads();

  // ---- P3: tok embed (fp32, K=12) + mask + ln1 -> Ab[:,0:64]; tok -> Tk ----
  // NOTE: overwrites OBSf region (Tk) and Df region (Ab) — both dead.
  for (int r=wv*15; r<wv*15+15; r++){
    float acc = a.tok_b[lane];
    #pragma unroll
    for (int k=0;k<12;k++) acc += TOKIN[r*12+k]*a.tok_w[k*64+lane];
    float t = gelu_f(acc)*mf[r];
    Tk[r*72+lane] = (__bf16)t;
    float m = wsum(t)*(1.f/64.f);
    float d = t-m;
    float v = wsum(d*d)*(1.f/64.f);
    Ab[r*136+lane] = (__bf16)(d*(1.0f/sqrtf(v+1e-6f))*a.ln1_s[lane]+a.ln1_b[lane]);
  }
  __syncthreads();

  // ---- K,V,Q projections (all read Ab[:,0:64]; V parks in Ab[:,64:128]) ----
  gemmW(Ab,136,4, ws+W_A1K,64,4,2, a.a1_kb, wv,lane,
    [&](int r0,int cn,v4f c){
      #pragma unroll
      for (int r=0;r<4;r++) Bb[(r0+r)*136+64+cn]=(__bf16)c[r]; });
  gemmW(Ab,136,4, ws+W_A1V,64,4,2, a.a1_vb, wv,lane,
    [&](int r0,int cn,v4f c){
      #pragma unroll
      for (int r=0;r<4;r++) Ab[(r0+r)*136+64+cn]=(__bf16)c[r]; });
  gemmW(Ab,136,4, ws+W_A1Q,64,4,2, a.a1_qb, wv,lane,
    [&](int r0,int cn,v4f c){
      #pragma unroll
      for (int r=0;r<4;r++) Bb[(r0+r)*136+cn]=(__bf16)c[r]; });
  __syncthreads();

  // ---- attn weights (vectorized b128 bf16 loads) ----
  if (tid<240){
    int tg=tid/20, rem=tid-tg*20, h=rem/5, i=rem-h*5;
    bool mi = msf[tg*5+i]>0.5f;
    float q[16]; load16f(&Bb[(tg*5+i)*136 + h*16], q);
    float lgv[5], mx=NEG_INF_F;
    #pragma unroll
    for (int j=0;j<5;j++){
      float kk[16]; load16f(&Bb[(tg*5+j)*136 + 64 + h*16], kk);
      float d=0.f;
      #pragma unroll
      for (int dd=0;dd<16;dd++) d += q[dd]*kk[dd];
      bool mj = msf[tg*5+j]>0.5f;
      lgv[j] = (mi&&mj)? d*0.25f : NEG_INF_F;
      mx = fmaxf(mx,lgv[j]);
    }
    float sum=0.f, ex[5];
    #pragma unroll
    for (int j=0;j<5;j++){ ex[j]=__expf(lgv[j]-mx); sum+=ex[j]; }
    float inv=1.0f/sum;
    #pragma unroll
    for (int j=0;j<5;j++) ATTb[tg*100+(h*5+i)*5+j]=(__bf16)(ex[j]*inv);
  }
  __syncthreads();

  // ---- o = attn @ V -> Ab[:,0:64] (wave-private rows/tokens) ----
  for (int r=wv*15; r<wv*15+15; r++){
    int tg=r/5, i=r-tg*5, h=lane>>4;
    float o=0.f;
    #pragma unroll
    for (int j=0;j<5;j++)
      o += (float)ATTb[tg*100+(h*5+i)*5+j]*(float)Ab[(tg*5+j)*136+64+lane];
    Ab[r*136+lane]=(__bf16)o;
  }
  __syncthreads();

  // ---- o-proj + residual -> Tk ----
  gemmW(Ab,136,4, ws+W_A1O,64,4,2, a.a1_ob, wv,lane,
    [&](int r0,int cn,v4f c){
      #pragma unroll
      for (int r=0;r<4;r++){
        int R=r0+r;
        Tk[R*72+cn] = (__bf16)((float)Tk[R*72+cn] + c[r]*mf[R]);
      } });
  __syncthreads();

  // ---- ln2 -> Ab[:,0:64] ----
  for (int r=wv*15; r<wv*15+15; r++){
    float x = (float)Tk[r*72+lane];
    float m = wsum(x)*(1.f/64.f);
    float d = x-m;
    float v = wsum(d*d)*(1.f/64.f);
    Ab[r*136+lane] = (__bf16)(d*(1.0f/sqrtf(v+1e-6f))*a.ln2_s[lane]+a.ln2_b[lane]);
  }
  __syncthreads();

  // ---- slot MLP ----
  gemmW(Ab,136,4, ws+W_M1,64,8,2, a.m1_b, wv,lane,
    [&](int r0,int cn,v4f c){
      #pragma unroll
      for (int r=0;r<4;r++) Bb[(r0+r)*136+cn]=(__bf16)gelu_f(c[r]); });
  __syncthreads();
  gemmW(Bb,136,4, ws+W_M2,128,8,4, a.m2_b, wv,lane,
    [&](int r0,int cn,v4f c){
      #pragma unroll
      for (int r=0;r<4;r++) Ab[(r0+r)*136+cn]=(__bf16)gelu_f(c[r]); });
  __syncthreads();
  // m3 (Ab->Tk) and e1 (Eg->Bb) are independent: same phase, no barrier between
  gemmW(Ab,136,4, ws+W_M3,128,4,4, a.m3_b, wv,lane,
    [&](int r0,int cn,v4f c){
      #pragma unroll
      for (int r=0;r<4;r++){
        int R=r0+r; float mm=mf[R];
        Tk[R*72+cn] = (__bf16)(((float)Tk[R*72+cn] + c[r]*mm)*mm);
      } });
  gemmW(Eg,40,1, ws+W_E1,32,8,1, a.e1_b, wv,lane,
    [&](int r0,int cn,v4f c){
      #pragma unroll
      for (int r=0;r<4;r++) Bb[(r0+r)*136+cn]=(__bf16)gelu_f(c[r]); });
  __syncthreads();
  gemmW(Bb,136,1, ws+W_E2,128,8,4, a.e2_b, wv,lane,
    [&](int r0,int cn,v4f c){
      #pragma unroll
      for (int r=0;r<4;r++) Ab[(r0+r)*136+cn]=(__bf16)gelu_f(c[r]); });
  __syncthreads();
  gemmW(Ab,136,1, ws+W_E3,128,4,4, a.e3_b, wv,lane,
    [&](int r0,int cn,v4f c){
      #pragma unroll
      for (int r=0;r<4;r++) ECX[(r0+r)*64+cn]=(__bf16)c[r]; });
  __syncthreads();

  // ---- build l1 input: Ab[:,0:64]=tok, [64:128]=ego_ctx ----
  for (int it=tid; it<60*64; it+=256){
    int r=it>>6, c=it&63;
    Ab[r*136+c]    = Tk[r*72+c];
    Ab[r*136+64+c] = ECX[(r/5)*64+c];
  }
  __syncthreads();

  // ---- l1, l2 ----
  gemmW(Ab,136,4, ws+W_L1,128,8,4, a.l1_b, wv,lane,
    [&](int r0,int cn,v4f c){
      #pragma unroll
      for (int r=0;r<4;r++) Bb[(r0+r)*136+cn]=(__bf16)gelu_f(c[r]); });
  __syncthreads();
  gemmW(Bb,136,4, ws+W_L2,128,8,4, a.l2_b, wv,lane,
    [&](int r0,int cn,v4f c){
      #pragma unroll
      for (int r=0;r<4;r++) Ab[(r0+r)*136+cn]=(__bf16)gelu_f(c[r]); });
  __syncthreads();

  // ---- l3 logits ----
  {
    float wA = a.l3_w[lane], wB = a.l3_w[64+lane];
    for (int r=wv*15; r<wv*15+15; r++){
      float v = (float)Ab[r*136+lane]*wA + (float)Ab[r*136+64+lane]*wB;
      v = wsum(v);
      if (lane==0) lg[r] = v + a.l3_b[0];
    }
  }
  __syncthreads();
  // alpha softmax + pooling kp/vp (independent: kp/vp read Tk, write dead Bb)
  if (tid<12){
    float ml[5], mx=-1e9f;
    #pragma unroll
    for (int i=0;i<5;i++){ ml[i]=(mf[tid*5+i]>0.5f)? lg[tid*5+i] : -1e9f; mx=fmaxf(mx,ml[i]); }
    float den=0.f;
    #pragma unroll
    for (int i=0;i<5;i++){ float e=__expf(ml[i]-mx)*mf[tid*5+i]; alpha[tid*5+i]=e; den+=e; }
    float inv=1.0f/(den+1e-9f);
    #pragma unroll
    for (int i=0;i<5;i++) alpha[tid*5+i]*=inv;
  }
  gemmW(Tk,72,4, ws+W_PK,64,4,2, a.p_kb, wv,lane,
    [&](int r0,int cn,v4f c){
      #pragma unroll
      for (int r=0;r<4;r++) Bb[(r0+r)*136+cn]=(__bf16)c[r]; });
  gemmW(Tk,72,4, ws+W_PV,64,4,2, a.p_vb, wv,lane,
    [&](int r0,int cn,v4f c){
      #pragma unroll
      for (int r=0;r<4;r++) Bb[(r0+r)*136+64+cn]=(__bf16)c[r]; });
  __syncthreads();

  // ---- v_r/v_u out + pooling attn weights ----
  if (tid<72){
    int tg=tid/6, c=tid-tg*6;
    float v=0.f;
    #pragma unroll
    for (int i=0;i<5;i++) v += alpha[tg*5+i]*Ru[tg*32+i*6+c];
    if (t0+tg<ntok) a.out[(t0+tg)*134+128+c]=v;
  }
  if (tid>=128 && tid<176){
    int it=tid-128, tg=it>>2, h=it&3;
    float lgv[5], mx=NEG_INF_F;
    #pragma unroll
    for (int j=0;j<5;j++){
      float kk[16]; load16f(&Bb[(tg*5+j)*136 + h*16], kk);
      float d=0.f;
      #pragma unroll
      for (int dd=0;dd<16;dd++) d += qp[h*16+dd]*kk[dd];
      lgv[j] = (msf[tg*5+j]>0.5f)? d*0.25f : NEG_INF_F;
      mx = fmaxf(mx,lgv[j]);
    }
    float sum=0.f, ex[5];
    #pragma unroll
    for (int j=0;j<5;j++){ ex[j]=__expf(lgv[j]-mx); sum+=ex[j]; }
    float inv=1.0f/sum;
    #pragma unroll
    for (int j=0;j<5;j++) pattn[tg*20+h*5+j]=ex[j]*inv;
  }
  __syncthreads();

  // ---- pooled c -> Ab rows 0..11 [0:64]; pe -> [64:128] ----
  for (int it=tid; it<12*64; it+=256){
    int tg=it>>6, c=it&63, h=c>>4;
    float o=0.f;
    #pragma unroll
    for (int j=0;j<5;j++)
      o += pattn[tg*20+h*5+j]*(float)Bb[(tg*5+j)*136+64+c];
    Ab[tg*136+c]=(__bf16)o;
    Ab[tg*136+64+c]=Pe[tg*64+c];
  }
  __syncthreads();

  // ---- p_ow (in-place on Ab rows 0..15: compute, sync, then write) ----
  {
    const int col=lane&15, quad=lane>>4;
    int nt=wv;
    v4f c; float b0=a.p_ob[nt*16+col];
    c[0]=b0; c[1]=b0; c[2]=b0; c[3]=b0;
    const __bf16* ap = Ab + (size_t)col*136 + quad*8;
    const __bf16* bp = ws + W_PO + (size_t)(nt*16+col)*64 + quad*8;
    #pragma unroll
    for (int kt=0;kt<2;kt++){
      v8bf av=*(const v8bf*)(ap+kt*32);
      v8bf bv=*(const v8bf*)(bp+kt*32);
      c=__builtin_amdgcn_mfma_f32_16x16x32_bf16(av,bv,c,0,0,0);
    }
    __syncthreads();
    #pragma unroll
    for (int r=0;r<4;r++){
      int R=quad*4+r;
      Ab[R*136 + nt*16+col] = (__bf16)(c[r]*many[R]);
    }
  }
  __syncthreads();

  // ---- h1: ego K=32 + [c|pe] K=128 ----
  {
    const int col=lane&15, quad=lane>>4;
    for (int t=wv; t<8; t+=4){
      int nt=t;
      v4f c; float b0=a.h1_b[nt*16+col];
      c[0]=b0; c[1]=b0; c[2]=b0; c[3]=b0;
      {
        v8bf av=*(const v8bf*)(Eg + (size_t)col*40 + quad*8);
        v8bf bv=*(const v8bf*)(ws + W_H1 + (size_t)(nt*16+col)*160 + quad*8);
        c=__builtin_amdgcn_mfma_f32_16x16x32_bf16(av,bv,c,0,0,0);
      }
      #pragma unroll
      for (int kt=0;kt<4;kt++){
        v8bf av=*(const v8bf*)(Ab + (size_t)col*136 + kt*32 + quad*8);
        v8bf bv=*(const v8bf*)(ws + W_H1 + (size_t)(nt*16+col)*160 + 32 + kt*32 + quad*8);
        c=__builtin_amdgcn_mfma_f32_16x16x32_bf16(av,bv,c,0,0,0);
      }
      #pragma unroll
      for (int r=0;r<4;r++) Bb[(quad*4+r)*136 + nt*16+col]=(__bf16)gelu_f(c[r]);
    }
  }
  __syncthreads();

  // ---- h2 ----
  gemmW(Bb,136,1, ws+W_H2,128,8,4, a.h2_b, wv,lane,
    [&](int r0,int cn,v4f c){
      #pragma unroll
      for (int r=0;r<4;r++) Ab[(r0+r)*136+cn]=(__bf16)gelu_f(c[r]); });
  __syncthreads();

  // ---- h3 -> out ----
  gemmW(Ab,136,1, ws+W_H3,128,8,4, a.h3_b, wv,lane,
    [&](int r0,int cn,v4f c){
      #pragma unroll
      for (int r=0;r<4;r++){
        int row = r0+r;
        long tk = t0 + row;
        if (row<12 && tk<ntok) a.out[tk*134+cn]=c[r];
      } });
}

extern "C" void kernel_launch(void* const* d_in, const int* in_sizes, int n_in,
                              void* d_out, int out_size, void* d_ws, size_t ws_size,
                              hipStream_t stream)
{
  P a;
  const float** pp = reinterpret_cast<const float**>(&a);
  for (int i=0;i<50;i++) pp[i] = reinterpret_cast<const float*>(d_in[i]);
  a.out = reinterpret_cast<float*>(d_out);
  int ntok = in_sizes[0] / DOBS;   // 65536

  __bf16* ws = reinterpret_cast<__bf16*>(d_ws);
  hipLaunchKernelGGL(prep_w, dim3(172), dim3(256), 0, stream, a, ws);
  hipLaunchKernelGGL(swarm_mfma, dim3((ntok+11)/12), dim3(256), 0, stream, a, ws, ntok);
}